// Round 14
// baseline (2467.575 us; speedup 1.0000x reference)
//
#include <hip/hip_runtime.h>

// PointNet++ SetAbstraction: FPS -> ball query -> grouped MLP(67->64->64->128, BN+ReLU) -> maxpool
// B=8, N=8192, S=2048, K=32, F=64.
//
// d_out: [8][2048][3] center_xyzs then [8][2048][128] center_feats (fp32).
// d_ws: 16576 floats of transposed weights.
//
// EXACTNESS INVARIANTS (validated R4..R13: absmax 7.8e-3 < 5.4e-2):
//   - discrete-decision math contraction-free (contract(off) helpers).
//   - np.sum last-axis n=3: FORWARD plain adds (x0+x1)+x2  [FPS dist, |c|^2, |x|^2]
//   - einsum dot: ascending FMA chain fma(c2,x2, fma(c1,x1, c0*x0))  [ball query]
//   - FPS argmax: u64 key (float_bits(bv)<<13)|(8191-idx); total order.
//   - dual argmax chains: chain1 indices all > chain0; strict > merge.
//   - MLP accumulation order ascending-c preserved across layout changes.
//
// PERF LESSONS:
//   R5: dynamically-indexed per-thread arrays get LDS-demoted — named/unrolled only.
//   R6/R7: __shfl_* lowers to ds_permute (LDS pipe) — use DPP for reductions.
//   R8..R11: FPS 256thr/1-wave-per-SIMD best; barrier cost scales with waves.
//   R13: v_pk inline asm REGRESSED FPS (marshaling+sched loss) — reverted.
//        sa o-split 2 waves/block WIN (529->487) — kept.
//   R14: sa LDS-pipe was the limiter (~2200 ds_read_b32/block @5.8cyc/inst):
//        stride 65/67 -> 68, c-loop chunked by 4, a-reads ds_read_b128,
//        layer-out ds_write_b128. K=67 tail: col67 zero-padded (w "row 67"
//        reads w2T row0: finite x 0 = exact no-op).

#define NPTS 8192
#define SCTR 2048
#define NB   8
#define KNN  32
#define NF   64

// (x*x + y*y) + z*z, NO contraction (np.sum forward order, n=3).
__device__ __forceinline__ float sumsq3(float x, float y, float z) {
#pragma clang fp contract(off)
  return (x * x + y * y) + z * z;
}

// FPS distance: (dx*dx + dy*dy) + dz*dz, exact order, NO contraction.
__device__ __forceinline__ float fps_sqdist(float ax, float ay, float az,
                                            float bx, float by, float bz) {
#pragma clang fp contract(off)
  float dx = ax - bx;
  float dy = ay - by;
  float dz = az - bz;
  return (dx * dx + dy * dy) + dz * dz;
}

// Ball-query expanded form: (sc + sx) - 2*dot, NO contraction on the adds.
__device__ __forceinline__ float bq_d2(float sc, float sx,
                                       float cx, float cy, float cz,
                                       float x, float y, float z) {
#pragma clang fp contract(off)
  float dt = fmaf(cz, z, fmaf(cy, y, cx * x));
  return (sc + sx) - 2.0f * dt;
}

// u64 max with the partner lane's key fetched via DPP (VALU pipe, no LDS).
template <int CTRL>
__device__ __forceinline__ unsigned long long kmax_dpp(unsigned long long k) {
  int lo = (int)(unsigned int)(k & 0xFFFFFFFFull);
  int hi = (int)(unsigned int)(k >> 32);
  int slo = __builtin_amdgcn_update_dpp(lo, lo, CTRL, 0xF, 0xF, false);
  int shi = __builtin_amdgcn_update_dpp(hi, hi, CTRL, 0xF, 0xF, false);
  unsigned long long sk =
      ((unsigned long long)(unsigned int)shi << 32) | (unsigned int)slo;
  return sk > k ? sk : k;
}

// ---------------------------------------------------------------------------
// Kernel 1 (R12-validated scalar version, pk-asm reverted): blocks 0..7 = FPS
// (256 thr = 4 waves = 1/SIMD, 32 pts/thread in NAMED float4 regs, dual
// argmax chains, DPP reductions); blocks 8..72 = weight transpose.
// ---------------------------------------------------------------------------
__global__ __launch_bounds__(256, 1) void fps_transpose_kernel(
    const float* __restrict__ xyzs,
    const float* __restrict__ w1, const float* __restrict__ w2, const float* __restrict__ w3,
    float* __restrict__ centers, float* __restrict__ wT)
{
  const int t = threadIdx.x;
  if (blockIdx.x >= NB) {
    int idx = (blockIdx.x - NB) * 256 + t;
    if (idx < 67*64) {
      int c = idx >> 6, o = idx & 63;
      wT[idx] = w1[o*67 + c];
    } else if (idx < 67*64 + 64*64) {
      int r = idx - 67*64; int c = r >> 6, o = r & 63;
      wT[idx] = w2[o*64 + c];
    } else if (idx < 67*64 + 64*64 + 64*128) {
      int r = idx - (67*64 + 64*64); int c = r >> 7, o = r & 127;
      wT[idx] = w3[o*64 + c];
    }
    return;
  }

  const int b = blockIdx.x;
  const float* xb = xyzs + (size_t)b * NPTS * 3;

  __shared__ float sX[NPTS], sY[NPTS], sZ[NPTS];         // 96 KB planar coords
  __shared__ unsigned long long redk[2][4];              // wave-best keys
  __shared__ int hist[SCTR];                             // 8 KB

  for (int i = t; i < NPTS; i += 256) {
    sX[i] = xb[3*i+0];
    sY[i] = xb[3*i+1];
    sZ[i] = xb[3*i+2];
  }
  if (t == 0) hist[0] = 0;   // reference: first center is index 0
  __syncthreads();

  const int t4 = 4 * t;

  // 32 loop-invariant points (8 quads strided 1024) in NAMED registers.
  const float4 xA = *(const float4*)(sX + 0    + t4);
  const float4 yA = *(const float4*)(sY + 0    + t4);
  const float4 zA = *(const float4*)(sZ + 0    + t4);
  const float4 xB = *(const float4*)(sX + 1024 + t4);
  const float4 yB = *(const float4*)(sY + 1024 + t4);
  const float4 zB = *(const float4*)(sZ + 1024 + t4);
  const float4 xC = *(const float4*)(sX + 2048 + t4);
  const float4 yC = *(const float4*)(sY + 2048 + t4);
  const float4 zC = *(const float4*)(sZ + 2048 + t4);
  const float4 xD = *(const float4*)(sX + 3072 + t4);
  const float4 yD = *(const float4*)(sY + 3072 + t4);
  const float4 zD = *(const float4*)(sZ + 3072 + t4);
  const float4 xE = *(const float4*)(sX + 4096 + t4);
  const float4 yE = *(const float4*)(sY + 4096 + t4);
  const float4 zE = *(const float4*)(sZ + 4096 + t4);
  const float4 xF = *(const float4*)(sX + 5120 + t4);
  const float4 yF = *(const float4*)(sY + 5120 + t4);
  const float4 zF = *(const float4*)(sZ + 5120 + t4);
  const float4 xG = *(const float4*)(sX + 6144 + t4);
  const float4 yG = *(const float4*)(sY + 6144 + t4);
  const float4 zG = *(const float4*)(sZ + 6144 + t4);
  const float4 xH = *(const float4*)(sX + 7168 + t4);
  const float4 yH = *(const float4*)(sY + 7168 + t4);
  const float4 zH = *(const float4*)(sZ + 7168 + t4);

  float4 mA = make_float4(1e10f,1e10f,1e10f,1e10f);
  float4 mB = mA, mC = mA, mD = mA, mE = mA, mF = mA, mG = mA, mH = mA;

  float lx = sX[0], ly = sY[0], lz = sZ[0];

#define FPS_QUAD(QX, QY, QZ, MV, QOFF, BV, BG)                                  \
  do {                                                                          \
    float d;                                                                    \
    d = fps_sqdist(QX.x, QY.x, QZ.x, lx, ly, lz);                               \
    MV.x = fminf(MV.x, d); if (MV.x > BV) { BV = MV.x; BG = (QOFF)+t4+0; }      \
    d = fps_sqdist(QX.y, QY.y, QZ.y, lx, ly, lz);                               \
    MV.y = fminf(MV.y, d); if (MV.y > BV) { BV = MV.y; BG = (QOFF)+t4+1; }      \
    d = fps_sqdist(QX.z, QY.z, QZ.z, lx, ly, lz);                               \
    MV.z = fminf(MV.z, d); if (MV.z > BV) { BV = MV.z; BG = (QOFF)+t4+2; }      \
    d = fps_sqdist(QX.w, QY.w, QZ.w, lx, ly, lz);                               \
    MV.w = fminf(MV.w, d); if (MV.w > BV) { BV = MV.w; BG = (QOFF)+t4+3; }      \
  } while (0)

  for (int s = 1; s < SCTR; ++s) {
    float bv0 = -1.0f, bv1 = -1.0f; int bg0 = 0, bg1 = 0;
    FPS_QUAD(xA, yA, zA, mA, 0,    bv0, bg0);
    FPS_QUAD(xB, yB, zB, mB, 1024, bv0, bg0);
    FPS_QUAD(xC, yC, zC, mC, 2048, bv0, bg0);
    FPS_QUAD(xD, yD, zD, mD, 3072, bv0, bg0);
    FPS_QUAD(xE, yE, zE, mE, 4096, bv1, bg1);
    FPS_QUAD(xF, yF, zF, mF, 5120, bv1, bg1);
    FPS_QUAD(xG, yG, zG, mG, 6144, bv1, bg1);
    FPS_QUAD(xH, yH, zH, mH, 7168, bv1, bg1);

    float bv = bv0; int bg = bg0;
    if (bv1 > bv0) { bv = bv1; bg = bg1; }   // strict > keeps smaller-index chain

    unsigned long long key =
        ((unsigned long long)__float_as_uint(bv) << 13) |
        (unsigned long long)(8191 - bg);

    key = kmax_dpp<0x111>(key);   // row_shr:1
    key = kmax_dpp<0x112>(key);   // row_shr:2
    key = kmax_dpp<0x114>(key);   // row_shr:4
    key = kmax_dpp<0x118>(key);   // row_shr:8
    key = kmax_dpp<0x142>(key);   // row_bcast:15
    key = kmax_dpp<0x143>(key);   // row_bcast:31

    int pb = s & 1;
    if ((t & 63) == 63) redk[pb][t >> 6] = key;
    __syncthreads();

    unsigned long long k4 = redk[pb][t & 3];
    k4 = kmax_dpp<0xB1>(k4);      // quad_perm [1,0,3,2]
    k4 = kmax_dpp<0x4E>(k4);      // quad_perm [2,3,0,1]

    int i0 = 8191 - (int)(k4 & 0x1FFFull);
    lx = sX[i0]; ly = sY[i0]; lz = sZ[i0];
    if (t == 0) hist[s] = i0;
  }
#undef FPS_QUAD
  __syncthreads();

  for (int s = t; s < SCTR; s += 256) {
    int i = hist[s];
    float* o = centers + ((size_t)b * SCTR + s) * 3;
    o[0] = sX[i]; o[1] = sY[i]; o[2] = sZ[i];
  }
}

// ---------------------------------------------------------------------------
// Kernel 2: 128 threads (2 waves) per center, o-split (R13-validated) +
// R14 LDS vectorization: stride 68, c-loop chunked by 4, a-reads as
// ds_read_b128, layer outputs as ds_write_b128. Accumulation order unchanged.
// ---------------------------------------------------------------------------
__global__ __launch_bounds__(128) void sa_fused_kernel(
    const float* __restrict__ xyzs, const float* __restrict__ feats,
    const float* centers, const float* __restrict__ wT,
    const float* __restrict__ b1, const float* __restrict__ g1, const float* __restrict__ bt1,
    const float* __restrict__ m1, const float* __restrict__ v1,
    const float* __restrict__ b2, const float* __restrict__ g2, const float* __restrict__ bt2,
    const float* __restrict__ m2, const float* __restrict__ v2,
    const float* __restrict__ b3, const float* __restrict__ g3, const float* __restrict__ bt3,
    const float* __restrict__ m3, const float* __restrict__ v3,
    float* out_feats)
{
  constexpr float R2 = (float)(0.2 * 0.2);
  const int bid  = blockIdx.x;
  const int b    = bid >> 11;
  const int tid  = threadIdx.x;
  const int w    = tid >> 6;       // wave id 0/1
  const int lane = tid & 63;
  const float* xb = xyzs + (size_t)b * NPTS * 3;
  const float* cp = centers + (size_t)bid * 3;
  float cx = cp[0], cy = cp[1], cz = cp[2];
  float sc = sumsq3(cx, cy, cz);

  __shared__ int   gidx[KNN];
  __shared__ float in_[32*68];   // [k][c] stride 68, col 67 zero pad
  __shared__ float y_[32*68];    // [k][c] stride 68

  // ---- ball query (both waves identical; duplicate writes benign) ----
  int cnt = 0;
  for (int base = 0; base < NPTS && cnt < KNN; base += 64) {
    int n = base + lane;
    float x = xb[n*3+0], y = xb[n*3+1], z = xb[n*3+2];
    float sx = sumsq3(x, y, z);
    float d2 = bq_d2(sc, sx, cx, cy, cz, x, y, z);
    bool within = (d2 <= R2);
    unsigned long long mk = __ballot(within);
    int rank = __popcll(mk & ((1ull << lane) - 1ull));
    int slot = cnt + rank;
    if (within && slot < KNN) gidx[slot] = n;
    cnt += (int)__popcll(mk);
  }
  if (cnt > KNN) cnt = KNN;
  __syncthreads();

  // ---- gather (2 waves, interleaved k): in_[k][0..2]=xyz-c, [3..66]=feats,
  // [67]=0 pad ----
#pragma unroll 4
  for (int k2 = 0; k2 < 16; ++k2) {
    int k = 2*k2 + w;
    int gk = (k < cnt) ? gidx[k] : -1;
    float fv = 0.f, xv = 0.f;
    if (gk >= 0) {
      fv = feats[((size_t)b * NPTS + gk) * NF + lane];
      if (lane < 3) xv = xb[gk*3 + lane] - cp[lane];  // exact single op
    }
    in_[k*68 + 3 + lane] = fv;
    if (lane < 3) in_[k*68 + lane] = xv;
    if (lane == 3) in_[k*68 + 67] = 0.f;
  }
  __syncthreads();

  const int g  = lane >> 3;        // k-group: k = 4g..4g+3
  const int h  = lane & 7;         // o-subgroup
  const int ob = w*32 + 4*h;       // wave's o-base for L1/L2
  const float* w1T = wT;                  // [67][64]
  const float* w2T = wT + 67*64;          // [64][64]
  const float* w3T = wT + 67*64 + 64*64;  // [64][128]

// One c-column: 16 fmas, a-scalars from the chunk's float4s.
#define FMA_COL(AS0, AS1, AS2, AS3, WV)                                      \
  do {                                                                       \
    acc[0][0]=fmaf(AS0, WV.x, acc[0][0]); acc[0][1]=fmaf(AS0, WV.y, acc[0][1]); \
    acc[0][2]=fmaf(AS0, WV.z, acc[0][2]); acc[0][3]=fmaf(AS0, WV.w, acc[0][3]); \
    acc[1][0]=fmaf(AS1, WV.x, acc[1][0]); acc[1][1]=fmaf(AS1, WV.y, acc[1][1]); \
    acc[1][2]=fmaf(AS1, WV.z, acc[1][2]); acc[1][3]=fmaf(AS1, WV.w, acc[1][3]); \
    acc[2][0]=fmaf(AS2, WV.x, acc[2][0]); acc[2][1]=fmaf(AS2, WV.y, acc[2][1]); \
    acc[2][2]=fmaf(AS2, WV.z, acc[2][2]); acc[2][3]=fmaf(AS2, WV.w, acc[2][3]); \
    acc[3][0]=fmaf(AS3, WV.x, acc[3][0]); acc[3][1]=fmaf(AS3, WV.y, acc[3][1]); \
    acc[3][2]=fmaf(AS3, WV.z, acc[3][2]); acc[3][3]=fmaf(AS3, WV.w, acc[3][3]); \
  } while (0)

// One 4-c chunk: 4 ds_read_b128 (a by k), 4 global float4 (w rows), 64 fmas.
#define MLP_CHUNK(SRC, WBASE, WSTRIDE, WOFF)                                 \
  do {                                                                       \
    float4 a0 = *(const float4*)(SRC + (4*g+0)*68 + c0);                     \
    float4 a1 = *(const float4*)(SRC + (4*g+1)*68 + c0);                     \
    float4 a2 = *(const float4*)(SRC + (4*g+2)*68 + c0);                     \
    float4 a3 = *(const float4*)(SRC + (4*g+3)*68 + c0);                     \
    float4 wv0 = *(const float4*)(WBASE + (c0+0)*(WSTRIDE) + (WOFF));        \
    float4 wv1 = *(const float4*)(WBASE + (c0+1)*(WSTRIDE) + (WOFF));        \
    float4 wv2 = *(const float4*)(WBASE + (c0+2)*(WSTRIDE) + (WOFF));        \
    float4 wv3 = *(const float4*)(WBASE + (c0+3)*(WSTRIDE) + (WOFF));        \
    FMA_COL(a0.x, a1.x, a2.x, a3.x, wv0);                                    \
    FMA_COL(a0.y, a1.y, a2.y, a3.y, wv1);                                    \
    FMA_COL(a0.z, a1.z, a2.z, a3.z, wv2);                                    \
    FMA_COL(a0.w, a1.w, a2.w, a3.w, wv3);                                    \
  } while (0)

  // ---- Layer 1: 67 -> 64 (K padded to 68; col67=0 x w2T-row0 = exact no-op) ----
  {
    float acc[4][4];
#pragma unroll
    for (int i=0;i<4;++i)
#pragma unroll
      for (int j=0;j<4;++j) acc[i][j]=0.f;
#pragma unroll 2
    for (int c0 = 0; c0 < 68; c0 += 4) {
      MLP_CHUNK(in_, w1T, 64, ob);
    }
    float scl[4], shf[4];
#pragma unroll
    for (int j=0;j<4;++j) {
      int o = ob + j;
      float r = g1[o] * rsqrtf(v1[o] + 1e-5f);
      scl[j] = r;
      shf[j] = (b1[o] - m1[o]) * r + bt1[o];
    }
#pragma unroll
    for (int i=0;i<4;++i) {
      float4 out;
      out.x = fmaxf(fmaf(acc[i][0], scl[0], shf[0]), 0.f);
      out.y = fmaxf(fmaf(acc[i][1], scl[1], shf[1]), 0.f);
      out.z = fmaxf(fmaf(acc[i][2], scl[2], shf[2]), 0.f);
      out.w = fmaxf(fmaf(acc[i][3], scl[3], shf[3]), 0.f);
      *(float4*)(y_ + (4*g+i)*68 + ob) = out;   // ds_write_b128
    }
  }
  __syncthreads();

  // ---- Layer 2: 64 -> 64 (reads y_, writes in_ o-half) ----
  {
    float acc[4][4];
#pragma unroll
    for (int i=0;i<4;++i)
#pragma unroll
      for (int j=0;j<4;++j) acc[i][j]=0.f;
#pragma unroll 2
    for (int c0 = 0; c0 < 64; c0 += 4) {
      MLP_CHUNK(y_, w2T, 64, ob);
    }
    float scl[4], shf[4];
#pragma unroll
    for (int j=0;j<4;++j) {
      int o = ob + j;
      float r = g2[o] * rsqrtf(v2[o] + 1e-5f);
      scl[j] = r;
      shf[j] = (b2[o] - m2[o]) * r + bt2[o];
    }
    __syncthreads();  // all y_ reads done before in_ overwrite (cross-wave)
#pragma unroll
    for (int i=0;i<4;++i) {
      float4 out;
      out.x = fmaxf(fmaf(acc[i][0], scl[0], shf[0]), 0.f);
      out.y = fmaxf(fmaf(acc[i][1], scl[1], shf[1]), 0.f);
      out.z = fmaxf(fmaf(acc[i][2], scl[2], shf[2]), 0.f);
      out.w = fmaxf(fmaf(acc[i][3], scl[3], shf[3]), 0.f);
      *(float4*)(in_ + (4*g+i)*68 + ob) = out;   // ds_write_b128
    }
  }
  __syncthreads();

  // ---- Layer 3: 64 -> 128; wave w owns o in [w*64, w*64+64) via 2 passes ----
  for (int p = 0; p < 2; ++p) {
    const int o3 = w*64 + p*32 + 4*h;
    float acc[4][4];
#pragma unroll
    for (int i=0;i<4;++i)
#pragma unroll
      for (int j=0;j<4;++j) acc[i][j]=0.f;
#pragma unroll 2
    for (int c0 = 0; c0 < 64; c0 += 4) {
      MLP_CHUNK(in_, w3T, 128, o3);
    }
    float scl[4], shf[4];
#pragma unroll
    for (int j=0;j<4;++j) {
      int o = o3 + j;
      float r = g3[o] * rsqrtf(v3[o] + 1e-5f);
      scl[j] = r;
      shf[j] = (b3[o] - m3[o]) * r + bt3[o];
    }
    float vm[4];
#pragma unroll
    for (int j=0;j<4;++j) {
      float q0 = fmaxf(fmaf(acc[0][j], scl[j], shf[j]), 0.f);
      float q1 = fmaxf(fmaf(acc[1][j], scl[j], shf[j]), 0.f);
      float q2 = fmaxf(fmaf(acc[2][j], scl[j], shf[j]), 0.f);
      float q3 = fmaxf(fmaf(acc[3][j], scl[j], shf[j]), 0.f);
      vm[j] = fmaxf(fmaxf(q0,q1), fmaxf(q2,q3));
    }
#pragma unroll
    for (int mk = 8; mk < 64; mk <<= 1) {
#pragma unroll
      for (int j=0;j<4;++j) vm[j] = fmaxf(vm[j], __shfl_xor(vm[j], mk));
    }
    if (g == 0) {
      float* dst = out_feats + (size_t)bid*128 + o3;
      *(float4*)dst = make_float4(vm[0], vm[1], vm[2], vm[3]);
    }
  }
#undef MLP_CHUNK
#undef FMA_COL
}

// ---------------------------------------------------------------------------
extern "C" void kernel_launch(void* const* d_in, const int* in_sizes, int n_in,
                              void* d_out, int out_size, void* d_ws, size_t ws_size,
                              hipStream_t stream) {
  const float* xyzs  = (const float*)d_in[0];
  const float* feats = (const float*)d_in[1];
  const float* w1  = (const float*)d_in[2];
  const float* b1  = (const float*)d_in[3];
  const float* g1  = (const float*)d_in[4];
  const float* bt1 = (const float*)d_in[5];
  const float* m1  = (const float*)d_in[6];
  const float* v1  = (const float*)d_in[7];
  const float* w2  = (const float*)d_in[8];
  const float* b2  = (const float*)d_in[9];
  const float* g2  = (const float*)d_in[10];
  const float* bt2 = (const float*)d_in[11];
  const float* m2  = (const float*)d_in[12];
  const float* v2  = (const float*)d_in[13];
  const float* w3  = (const float*)d_in[14];
  const float* b3  = (const float*)d_in[15];
  const float* g3  = (const float*)d_in[16];
  const float* bt3 = (const float*)d_in[17];
  const float* m3  = (const float*)d_in[18];
  const float* v3  = (const float*)d_in[19];

  float* out       = (float*)d_out;
  float* centers   = out;                          // [8][2048][3]
  float* out_feats = out + (size_t)NB * SCTR * 3;  // [8][2048][128]
  float* wT        = (float*)d_ws;                 // 16576 floats

  // blocks 0..7: FPS; blocks 8..72: weight transpose (65 blocks x 256 thr)
  hipLaunchKernelGGL(fps_transpose_kernel, dim3(NB + 65), dim3(256), 0, stream,
                     xyzs, w1, w2, w3, centers, wT);
  hipLaunchKernelGGL(sa_fused_kernel, dim3(NB * SCTR), dim3(128), 0, stream,
                     xyzs, feats, centers, wT,
                     b1, g1, bt1, m1, v1,
                     b2, g2, bt2, m2, v2,
                     b3, g3, bt3, m3, v3,
                     out_feats);
}

// Round 15
// 2300.223 us; speedup vs baseline: 1.0728x; 1.0728x over previous
//
#include <hip/hip_runtime.h>

// PointNet++ SetAbstraction: FPS -> ball query -> grouped MLP(67->64->64->128, BN+ReLU) -> maxpool
// B=8, N=8192, S=2048, K=32, F=64.
//
// d_out: [8][2048][3] center_xyzs then [8][2048][128] center_feats (fp32).
// d_ws: 16576 floats of transposed weights.
//
// EXACTNESS INVARIANTS (validated R4..R14: absmax 7.8e-3 < 5.4e-2):
//   - discrete-decision math contraction-free (contract(off) helpers).
//   - np.sum last-axis n=3: FORWARD plain adds (x0+x1)+x2  [FPS dist, |c|^2, |x|^2]
//   - einsum dot: ascending FMA chain fma(c2,x2, fma(c1,x1, c0*x0))  [ball query]
//   - FPS argmax: u64 key (float_bits(bv)<<13)|(8191-idx); total order.
//   - dual argmax chains: chain1 indices all > chain0; strict > merge.
//   - v2f ops round per-half identically to scalar (R9/R10-validated).
//   - MLP accumulation order ascending-c preserved across layout changes.
//
// PERF LESSONS (measured):
//   R5: dynamically-indexed per-thread arrays get LDS-demoted — named/unrolled only.
//   R6/R7: __shfl_* lowers to ds_permute (LDS pipe) — use DPP for reductions.
//   R8..R11: FPS 256thr/1-wave-per-SIMD best; barrier cost scales with waves.
//   R13/R14: FPS dist-loop source form ranking: v2f-source 1832us <
//       pk-inline-asm 1902us < explicit scalar 2000us. LLVM schedules the
//       vector-IR form best; keep fps_sqdist_v2 EXACTLY as-is.
//   R13: sa o-split 2 waves/block WIN (529->487). R14: +LDS b128 (stride 68,
//       4-c chunks) -> ~467us. 4-way bank conflicts eat part of the b128 win.
//   R15: combine best FPS (R11/R12) + best sa (R14). No new mechanisms.

#define NPTS 8192
#define SCTR 2048
#define NB   8
#define KNN  32
#define NF   64

typedef float v2f __attribute__((ext_vector_type(2)));

// d = (dx*dx + dy*dy) + dz*dz for TWO points, exact fp32 mul/add order,
// NO contraction. KEEP THIS SOURCE FORM (R13/R14: fastest measured variant).
__device__ __forceinline__ v2f fps_sqdist_v2(v2f px, v2f py, v2f pz,
                                             v2f lx, v2f ly, v2f lz) {
#pragma clang fp contract(off)
  v2f dx = px - lx;
  v2f dy = py - ly;
  v2f dz = pz - lz;
  v2f xx = dx * dx;
  v2f yy = dy * dy;
  v2f zz = dz * dz;
  return (xx + yy) + zz;
}

// (x*x + y*y) + z*z, NO contraction (np.sum forward order, n=3).
__device__ __forceinline__ float sumsq3(float x, float y, float z) {
#pragma clang fp contract(off)
  return (x * x + y * y) + z * z;
}

// Ball-query expanded form: (sc + sx) - 2*dot, NO contraction on the adds.
__device__ __forceinline__ float bq_d2(float sc, float sx,
                                       float cx, float cy, float cz,
                                       float x, float y, float z) {
#pragma clang fp contract(off)
  float dt = fmaf(cz, z, fmaf(cy, y, cx * x));
  return (sc + sx) - 2.0f * dt;
}

// u64 max with the partner lane's key fetched via DPP (VALU pipe, no LDS).
template <int CTRL>
__device__ __forceinline__ unsigned long long kmax_dpp(unsigned long long k) {
  int lo = (int)(unsigned int)(k & 0xFFFFFFFFull);
  int hi = (int)(unsigned int)(k >> 32);
  int slo = __builtin_amdgcn_update_dpp(lo, lo, CTRL, 0xF, 0xF, false);
  int shi = __builtin_amdgcn_update_dpp(hi, hi, CTRL, 0xF, 0xF, false);
  unsigned long long sk =
      ((unsigned long long)(unsigned int)shi << 32) | (unsigned int)slo;
  return sk > k ? sk : k;
}

// ---------------------------------------------------------------------------
// Kernel 1 (R11/R12-validated, 1832us): blocks 0..7 = FPS (256 thr = 4 waves
// = 1/SIMD, 32 pts/thread in NAMED float4 regs, v2f-source distances, dual
// argmax chains, DPP reductions); blocks 8..72 = weight transpose.
// ---------------------------------------------------------------------------
__global__ __launch_bounds__(256, 1) void fps_transpose_kernel(
    const float* __restrict__ xyzs,
    const float* __restrict__ w1, const float* __restrict__ w2, const float* __restrict__ w3,
    float* __restrict__ centers, float* __restrict__ wT)
{
  const int t = threadIdx.x;
  if (blockIdx.x >= NB) {
    int idx = (blockIdx.x - NB) * 256 + t;
    if (idx < 67*64) {
      int c = idx >> 6, o = idx & 63;
      wT[idx] = w1[o*67 + c];
    } else if (idx < 67*64 + 64*64) {
      int r = idx - 67*64; int c = r >> 6, o = r & 63;
      wT[idx] = w2[o*64 + c];
    } else if (idx < 67*64 + 64*64 + 64*128) {
      int r = idx - (67*64 + 64*64); int c = r >> 7, o = r & 127;
      wT[idx] = w3[o*64 + c];
    }
    return;
  }

  const int b = blockIdx.x;
  const float* xb = xyzs + (size_t)b * NPTS * 3;

  __shared__ float sX[NPTS], sY[NPTS], sZ[NPTS];         // 96 KB planar coords
  __shared__ unsigned long long redk[2][4];              // wave-best keys
  __shared__ int hist[SCTR];                             // 8 KB

  for (int i = t; i < NPTS; i += 256) {
    sX[i] = xb[3*i+0];
    sY[i] = xb[3*i+1];
    sZ[i] = xb[3*i+2];
  }
  if (t == 0) hist[0] = 0;   // reference: first center is index 0
  __syncthreads();

  const int t4 = 4 * t;

  // 32 loop-invariant points (8 quads strided 1024) in NAMED registers.
  const float4 xA = *(const float4*)(sX + 0    + t4);
  const float4 yA = *(const float4*)(sY + 0    + t4);
  const float4 zA = *(const float4*)(sZ + 0    + t4);
  const float4 xB = *(const float4*)(sX + 1024 + t4);
  const float4 yB = *(const float4*)(sY + 1024 + t4);
  const float4 zB = *(const float4*)(sZ + 1024 + t4);
  const float4 xC = *(const float4*)(sX + 2048 + t4);
  const float4 yC = *(const float4*)(sY + 2048 + t4);
  const float4 zC = *(const float4*)(sZ + 2048 + t4);
  const float4 xD = *(const float4*)(sX + 3072 + t4);
  const float4 yD = *(const float4*)(sY + 3072 + t4);
  const float4 zD = *(const float4*)(sZ + 3072 + t4);
  const float4 xE = *(const float4*)(sX + 4096 + t4);
  const float4 yE = *(const float4*)(sY + 4096 + t4);
  const float4 zE = *(const float4*)(sZ + 4096 + t4);
  const float4 xF = *(const float4*)(sX + 5120 + t4);
  const float4 yF = *(const float4*)(sY + 5120 + t4);
  const float4 zF = *(const float4*)(sZ + 5120 + t4);
  const float4 xG = *(const float4*)(sX + 6144 + t4);
  const float4 yG = *(const float4*)(sY + 6144 + t4);
  const float4 zG = *(const float4*)(sZ + 6144 + t4);
  const float4 xH = *(const float4*)(sX + 7168 + t4);
  const float4 yH = *(const float4*)(sY + 7168 + t4);
  const float4 zH = *(const float4*)(sZ + 7168 + t4);

  float4 mA = make_float4(1e10f,1e10f,1e10f,1e10f);
  float4 mB = mA, mC = mA, mD = mA, mE = mA, mF = mA, mG = mA, mH = mA;

  float lx = sX[0], ly = sY[0], lz = sZ[0];

#define FPS_QUAD(QX, QY, QZ, MV, QOFF, BV, BG)                                  \
  do {                                                                          \
    v2f d;                                                                      \
    d = fps_sqdist_v2((v2f){QX.x,QX.y}, (v2f){QY.x,QY.y}, (v2f){QZ.x,QZ.y},     \
                      lxv, lyv, lzv);                                           \
    MV.x = fminf(MV.x, d.x); if (MV.x > BV) { BV = MV.x; BG = (QOFF)+t4+0; }    \
    MV.y = fminf(MV.y, d.y); if (MV.y > BV) { BV = MV.y; BG = (QOFF)+t4+1; }    \
    d = fps_sqdist_v2((v2f){QX.z,QX.w}, (v2f){QY.z,QY.w}, (v2f){QZ.z,QZ.w},     \
                      lxv, lyv, lzv);                                           \
    MV.z = fminf(MV.z, d.x); if (MV.z > BV) { BV = MV.z; BG = (QOFF)+t4+2; }    \
    MV.w = fminf(MV.w, d.y); if (MV.w > BV) { BV = MV.w; BG = (QOFF)+t4+3; }    \
  } while (0)

  for (int s = 1; s < SCTR; ++s) {
    float bv0 = -1.0f, bv1 = -1.0f; int bg0 = 0, bg1 = 0;
    {
      v2f lxv = {lx, lx}, lyv = {ly, ly}, lzv = {lz, lz};
      FPS_QUAD(xA, yA, zA, mA, 0,    bv0, bg0);
      FPS_QUAD(xB, yB, zB, mB, 1024, bv0, bg0);
      FPS_QUAD(xC, yC, zC, mC, 2048, bv0, bg0);
      FPS_QUAD(xD, yD, zD, mD, 3072, bv0, bg0);
      FPS_QUAD(xE, yE, zE, mE, 4096, bv1, bg1);
      FPS_QUAD(xF, yF, zF, mF, 5120, bv1, bg1);
      FPS_QUAD(xG, yG, zG, mG, 6144, bv1, bg1);
      FPS_QUAD(xH, yH, zH, mH, 7168, bv1, bg1);
    }
    float bv = bv0; int bg = bg0;
    if (bv1 > bv0) { bv = bv1; bg = bg1; }   // strict > keeps smaller-index chain

    unsigned long long key =
        ((unsigned long long)__float_as_uint(bv) << 13) |
        (unsigned long long)(8191 - bg);

    key = kmax_dpp<0x111>(key);   // row_shr:1
    key = kmax_dpp<0x112>(key);   // row_shr:2
    key = kmax_dpp<0x114>(key);   // row_shr:4
    key = kmax_dpp<0x118>(key);   // row_shr:8
    key = kmax_dpp<0x142>(key);   // row_bcast:15
    key = kmax_dpp<0x143>(key);   // row_bcast:31

    int pb = s & 1;
    if ((t & 63) == 63) redk[pb][t >> 6] = key;
    __syncthreads();

    unsigned long long k4 = redk[pb][t & 3];
    k4 = kmax_dpp<0xB1>(k4);      // quad_perm [1,0,3,2]
    k4 = kmax_dpp<0x4E>(k4);      // quad_perm [2,3,0,1]

    int i0 = 8191 - (int)(k4 & 0x1FFFull);
    lx = sX[i0]; ly = sY[i0]; lz = sZ[i0];
    if (t == 0) hist[s] = i0;
  }
#undef FPS_QUAD
  __syncthreads();

  for (int s = t; s < SCTR; s += 256) {
    int i = hist[s];
    float* o = centers + ((size_t)b * SCTR + s) * 3;
    o[0] = sX[i]; o[1] = sY[i]; o[2] = sZ[i];
  }
}

// ---------------------------------------------------------------------------
// Kernel 2 (R14-validated, ~467us): 128 threads (2 waves) per center, o-split,
// stride-68 LDS with ds_read_b128 a-reads and ds_write_b128 layer outputs.
// K=67 tail handled by zero-padded col 67 (w "row 67" reads w2T row 0:
// finite x 0 = exact no-op). Accumulation order ascending-c unchanged.
// ---------------------------------------------------------------------------
__global__ __launch_bounds__(128) void sa_fused_kernel(
    const float* __restrict__ xyzs, const float* __restrict__ feats,
    const float* centers, const float* __restrict__ wT,
    const float* __restrict__ b1, const float* __restrict__ g1, const float* __restrict__ bt1,
    const float* __restrict__ m1, const float* __restrict__ v1,
    const float* __restrict__ b2, const float* __restrict__ g2, const float* __restrict__ bt2,
    const float* __restrict__ m2, const float* __restrict__ v2,
    const float* __restrict__ b3, const float* __restrict__ g3, const float* __restrict__ bt3,
    const float* __restrict__ m3, const float* __restrict__ v3,
    float* out_feats)
{
  constexpr float R2 = (float)(0.2 * 0.2);
  const int bid  = blockIdx.x;
  const int b    = bid >> 11;
  const int tid  = threadIdx.x;
  const int w    = tid >> 6;       // wave id 0/1
  const int lane = tid & 63;
  const float* xb = xyzs + (size_t)b * NPTS * 3;
  const float* cp = centers + (size_t)bid * 3;
  float cx = cp[0], cy = cp[1], cz = cp[2];
  float sc = sumsq3(cx, cy, cz);

  __shared__ int   gidx[KNN];
  __shared__ float in_[32*68];   // [k][c] stride 68, col 67 zero pad
  __shared__ float y_[32*68];    // [k][c] stride 68

  // ---- ball query (both waves identical; duplicate writes benign) ----
  int cnt = 0;
  for (int base = 0; base < NPTS && cnt < KNN; base += 64) {
    int n = base + lane;
    float x = xb[n*3+0], y = xb[n*3+1], z = xb[n*3+2];
    float sx = sumsq3(x, y, z);
    float d2 = bq_d2(sc, sx, cx, cy, cz, x, y, z);
    bool within = (d2 <= R2);
    unsigned long long mk = __ballot(within);
    int rank = __popcll(mk & ((1ull << lane) - 1ull));
    int slot = cnt + rank;
    if (within && slot < KNN) gidx[slot] = n;
    cnt += (int)__popcll(mk);
  }
  if (cnt > KNN) cnt = KNN;
  __syncthreads();

  // ---- gather (2 waves, interleaved k): in_[k][0..2]=xyz-c, [3..66]=feats,
  // [67]=0 pad ----
#pragma unroll 4
  for (int k2 = 0; k2 < 16; ++k2) {
    int k = 2*k2 + w;
    int gk = (k < cnt) ? gidx[k] : -1;
    float fv = 0.f, xv = 0.f;
    if (gk >= 0) {
      fv = feats[((size_t)b * NPTS + gk) * NF + lane];
      if (lane < 3) xv = xb[gk*3 + lane] - cp[lane];  // exact single op
    }
    in_[k*68 + 3 + lane] = fv;
    if (lane < 3) in_[k*68 + lane] = xv;
    if (lane == 3) in_[k*68 + 67] = 0.f;
  }
  __syncthreads();

  const int g  = lane >> 3;        // k-group: k = 4g..4g+3
  const int h  = lane & 7;         // o-subgroup
  const int ob = w*32 + 4*h;       // wave's o-base for L1/L2
  const float* w1T = wT;                  // [67][64]
  const float* w2T = wT + 67*64;          // [64][64]
  const float* w3T = wT + 67*64 + 64*64;  // [64][128]

// One c-column: 16 fmas, a-scalars from the chunk's float4s.
#define FMA_COL(AS0, AS1, AS2, AS3, WV)                                      \
  do {                                                                       \
    acc[0][0]=fmaf(AS0, WV.x, acc[0][0]); acc[0][1]=fmaf(AS0, WV.y, acc[0][1]); \
    acc[0][2]=fmaf(AS0, WV.z, acc[0][2]); acc[0][3]=fmaf(AS0, WV.w, acc[0][3]); \
    acc[1][0]=fmaf(AS1, WV.x, acc[1][0]); acc[1][1]=fmaf(AS1, WV.y, acc[1][1]); \
    acc[1][2]=fmaf(AS1, WV.z, acc[1][2]); acc[1][3]=fmaf(AS1, WV.w, acc[1][3]); \
    acc[2][0]=fmaf(AS2, WV.x, acc[2][0]); acc[2][1]=fmaf(AS2, WV.y, acc[2][1]); \
    acc[2][2]=fmaf(AS2, WV.z, acc[2][2]); acc[2][3]=fmaf(AS2, WV.w, acc[2][3]); \
    acc[3][0]=fmaf(AS3, WV.x, acc[3][0]); acc[3][1]=fmaf(AS3, WV.y, acc[3][1]); \
    acc[3][2]=fmaf(AS3, WV.z, acc[3][2]); acc[3][3]=fmaf(AS3, WV.w, acc[3][3]); \
  } while (0)

// One 4-c chunk: 4 ds_read_b128 (a by k), 4 global float4 (w rows), 64 fmas.
#define MLP_CHUNK(SRC, WBASE, WSTRIDE, WOFF)                                 \
  do {                                                                       \
    float4 a0 = *(const float4*)(SRC + (4*g+0)*68 + c0);                     \
    float4 a1 = *(const float4*)(SRC + (4*g+1)*68 + c0);                     \
    float4 a2 = *(const float4*)(SRC + (4*g+2)*68 + c0);                     \
    float4 a3 = *(const float4*)(SRC + (4*g+3)*68 + c0);                     \
    float4 wv0 = *(const float4*)(WBASE + (c0+0)*(WSTRIDE) + (WOFF));        \
    float4 wv1 = *(const float4*)(WBASE + (c0+1)*(WSTRIDE) + (WOFF));        \
    float4 wv2 = *(const float4*)(WBASE + (c0+2)*(WSTRIDE) + (WOFF));        \
    float4 wv3 = *(const float4*)(WBASE + (c0+3)*(WSTRIDE) + (WOFF));        \
    FMA_COL(a0.x, a1.x, a2.x, a3.x, wv0);                                    \
    FMA_COL(a0.y, a1.y, a2.y, a3.y, wv1);                                    \
    FMA_COL(a0.z, a1.z, a2.z, a3.z, wv2);                                    \
    FMA_COL(a0.w, a1.w, a2.w, a3.w, wv3);                                    \
  } while (0)

  // ---- Layer 1: 67 -> 64 (K padded to 68; col67=0 x w2T-row0 = exact no-op) ----
  {
    float acc[4][4];
#pragma unroll
    for (int i=0;i<4;++i)
#pragma unroll
      for (int j=0;j<4;++j) acc[i][j]=0.f;
#pragma unroll 2
    for (int c0 = 0; c0 < 68; c0 += 4) {
      MLP_CHUNK(in_, w1T, 64, ob);
    }
    float scl[4], shf[4];
#pragma unroll
    for (int j=0;j<4;++j) {
      int o = ob + j;
      float r = g1[o] * rsqrtf(v1[o] + 1e-5f);
      scl[j] = r;
      shf[j] = (b1[o] - m1[o]) * r + bt1[o];
    }
#pragma unroll
    for (int i=0;i<4;++i) {
      float4 out;
      out.x = fmaxf(fmaf(acc[i][0], scl[0], shf[0]), 0.f);
      out.y = fmaxf(fmaf(acc[i][1], scl[1], shf[1]), 0.f);
      out.z = fmaxf(fmaf(acc[i][2], scl[2], shf[2]), 0.f);
      out.w = fmaxf(fmaf(acc[i][3], scl[3], shf[3]), 0.f);
      *(float4*)(y_ + (4*g+i)*68 + ob) = out;   // ds_write_b128
    }
  }
  __syncthreads();

  // ---- Layer 2: 64 -> 64 (reads y_, writes in_ o-half) ----
  {
    float acc[4][4];
#pragma unroll
    for (int i=0;i<4;++i)
#pragma unroll
      for (int j=0;j<4;++j) acc[i][j]=0.f;
#pragma unroll 2
    for (int c0 = 0; c0 < 64; c0 += 4) {
      MLP_CHUNK(y_, w2T, 64, ob);
    }
    float scl[4], shf[4];
#pragma unroll
    for (int j=0;j<4;++j) {
      int o = ob + j;
      float r = g2[o] * rsqrtf(v2[o] + 1e-5f);
      scl[j] = r;
      shf[j] = (b2[o] - m2[o]) * r + bt2[o];
    }
    __syncthreads();  // all y_ reads done before in_ overwrite (cross-wave)
#pragma unroll
    for (int i=0;i<4;++i) {
      float4 out;
      out.x = fmaxf(fmaf(acc[i][0], scl[0], shf[0]), 0.f);
      out.y = fmaxf(fmaf(acc[i][1], scl[1], shf[1]), 0.f);
      out.z = fmaxf(fmaf(acc[i][2], scl[2], shf[2]), 0.f);
      out.w = fmaxf(fmaf(acc[i][3], scl[3], shf[3]), 0.f);
      *(float4*)(in_ + (4*g+i)*68 + ob) = out;   // ds_write_b128
    }
  }
  __syncthreads();

  // ---- Layer 3: 64 -> 128; wave w owns o in [w*64, w*64+64) via 2 passes ----
  for (int p = 0; p < 2; ++p) {
    const int o3 = w*64 + p*32 + 4*h;
    float acc[4][4];
#pragma unroll
    for (int i=0;i<4;++i)
#pragma unroll
      for (int j=0;j<4;++j) acc[i][j]=0.f;
#pragma unroll 2
    for (int c0 = 0; c0 < 64; c0 += 4) {
      MLP_CHUNK(in_, w3T, 128, o3);
    }
    float scl[4], shf[4];
#pragma unroll
    for (int j=0;j<4;++j) {
      int o = o3 + j;
      float r = g3[o] * rsqrtf(v3[o] + 1e-5f);
      scl[j] = r;
      shf[j] = (b3[o] - m3[o]) * r + bt3[o];
    }
    float vm[4];
#pragma unroll
    for (int j=0;j<4;++j) {
      float q0 = fmaxf(fmaf(acc[0][j], scl[j], shf[j]), 0.f);
      float q1 = fmaxf(fmaf(acc[1][j], scl[j], shf[j]), 0.f);
      float q2 = fmaxf(fmaf(acc[2][j], scl[j], shf[j]), 0.f);
      float q3 = fmaxf(fmaf(acc[3][j], scl[j], shf[j]), 0.f);
      vm[j] = fmaxf(fmaxf(q0,q1), fmaxf(q2,q3));
    }
#pragma unroll
    for (int mk = 8; mk < 64; mk <<= 1) {
#pragma unroll
      for (int j=0;j<4;++j) vm[j] = fmaxf(vm[j], __shfl_xor(vm[j], mk));
    }
    if (g == 0) {
      float* dst = out_feats + (size_t)bid*128 + o3;
      *(float4*)dst = make_float4(vm[0], vm[1], vm[2], vm[3]);
    }
  }
#undef MLP_CHUNK
#undef FMA_COL
}

// ---------------------------------------------------------------------------
extern "C" void kernel_launch(void* const* d_in, const int* in_sizes, int n_in,
                              void* d_out, int out_size, void* d_ws, size_t ws_size,
                              hipStream_t stream) {
  const float* xyzs  = (const float*)d_in[0];
  const float* feats = (const float*)d_in[1];
  const float* w1  = (const float*)d_in[2];
  const float* b1  = (const float*)d_in[3];
  const float* g1  = (const float*)d_in[4];
  const float* bt1 = (const float*)d_in[5];
  const float* m1  = (const float*)d_in[6];
  const float* v1  = (const float*)d_in[7];
  const float* w2  = (const float*)d_in[8];
  const float* b2  = (const float*)d_in[9];
  const float* g2  = (const float*)d_in[10];
  const float* bt2 = (const float*)d_in[11];
  const float* m2  = (const float*)d_in[12];
  const float* v2  = (const float*)d_in[13];
  const float* w3  = (const float*)d_in[14];
  const float* b3  = (const float*)d_in[15];
  const float* g3  = (const float*)d_in[16];
  const float* bt3 = (const float*)d_in[17];
  const float* m3  = (const float*)d_in[18];
  const float* v3  = (const float*)d_in[19];

  float* out       = (float*)d_out;
  float* centers   = out;                          // [8][2048][3]
  float* out_feats = out + (size_t)NB * SCTR * 3;  // [8][2048][128]
  float* wT        = (float*)d_ws;                 // 16576 floats

  // blocks 0..7: FPS; blocks 8..72: weight transpose (65 blocks x 256 thr)
  hipLaunchKernelGGL(fps_transpose_kernel, dim3(NB + 65), dim3(256), 0, stream,
                     xyzs, w1, w2, w3, centers, wT);
  hipLaunchKernelGGL(sa_fused_kernel, dim3(NB * SCTR), dim3(128), 0, stream,
                     xyzs, feats, centers, wT,
                     b1, g1, bt1, m1, v1,
                     b2, g2, bt2, m2, v2,
                     b3, g3, bt3, m3, v3,
                     out_feats);
}